// Round 3
// baseline (99.289 us; speedup 1.0000x reference)
//
#include <hip/hip_runtime.h>

// ChamferLoss: B=4, N=M=8192, D=3, fp32.
// loss = mean_b[ mean(pred2gt) + mean(gt2pred) + max(pred2gt) ]
// R11: FUSED kernel. R10 counters: nn_mfma 43.4us vs ~5us pipe floors, hbm ~0
//  -> latency-bound. Root cause: bfrag stream was wave-independent (bp has no
//  'w') => 4x redundant VMEM + unhidden L2/L3 latency (3255 cyc/pair-step
//  measured vs ~260 issue). Fix: compute B-frags in-block from raw y and
//  stage in LDS (double-buffered, 1 barrier/phase, 8 tiles/phase); drop the
//  yprep dispatch + bfrag round-trip entirely.
//   A row m (K=16): [xh0..2, xh0..2, xl0..2, 1, 1, 0...]
//   B col n (K=16): [-2yh0..2, -2yl0..2, -2yh0..2, y2h, y2l, 0]
//   D = y2 - 2(xh.yh + xh.yl + xl.yh); d2 = x2 + min_y D  (xl.yl ~2^-18 dropped)

typedef short  s16x8  __attribute__((ext_vector_type(8)));
typedef float  f32x16 __attribute__((ext_vector_type(16)));

#define BATCH 4
#define NPTS  8192
#define TPB   256
#define YS    4                    // y slices per (b,dir)
#define YPS   (NPTS / YS)          // 2048 y-points per slice
#define CTILES 8                   // tiles per LDS phase (256 pts, 1/thread)
#define NPH   (YPS / (CTILES * 32))// 8 phases
#define XPB   256                  // x per block: 4 waves x 2 tiles x 32
#define NXC   (NPTS / XPB)         // 32

__device__ __forceinline__ unsigned int bft(float f) { return __float_as_uint(f) >> 16; }
__device__ __forceinline__ float bfv(unsigned int s) { return __uint_as_float(s << 16); }

// Build the two packed B-frag words for one y point (identical math to the
// old yprep kernel; absmax 0.0 verified with this split).
__device__ __forceinline__ void yfrag(float a0, float a1, float a2,
                                      uint4& w0, uint4& w1) {
    const unsigned int yh0 = bft(a0), yh1 = bft(a1), yh2 = bft(a2);
    const float l0 = a0 - bfv(yh0), l1 = a1 - bfv(yh1), l2 = a2 - bfv(yh2);
    const unsigned int nh0 = bft(-2.f * bfv(yh0));     // exact in bf16
    const unsigned int nh1 = bft(-2.f * bfv(yh1));
    const unsigned int nh2 = bft(-2.f * bfv(yh2));
    const unsigned int nl0 = bft(-2.f * l0), nl1 = bft(-2.f * l1), nl2 = bft(-2.f * l2);
    const float y2 = a0 * a0 + a1 * a1 + a2 * a2;
    const unsigned int q2h = bft(y2);
    const unsigned int q2l = bft(y2 - bfv(q2h));
    w0.x = nh0 | (nh1 << 16);
    w0.y = nh2 | (nl0 << 16);
    w0.z = nl1 | (nl2 << 16);
    w0.w = nh0 | (nh1 << 16);
    w1.x = nh2 | (q2h << 16);
    w1.y = q2l;
    w1.z = 0u; w1.w = 0u;
}

__global__ __launch_bounds__(TPB, 4)
void nn_fused(const float* __restrict__ pred, const float* __restrict__ gt,
              unsigned int* __restrict__ pmin) {
    const int xc = blockIdx.x, sl = blockIdx.y, bd = blockIdx.z;
    const int b = bd >> 1, dir = bd & 1;
    const float* xp = (dir ? gt : pred) + (size_t)b * NPTS * 3;
    const float* yp = (dir ? pred : gt) + (size_t)b * NPTS * 3;

    const int t = threadIdx.x;
    const int w = t >> 6, l = t & 63;
    const int m32 = l & 31, hh = l >> 5;
    const int xbase = xc * XPB + w * 64;

    // LDS: double-buffered B-frag tiles. [buf][tile(8)*64 + {0..31:w0, 32..63:w1}]
    __shared__ uint4 ldsb[2][CTILES * 64];             // 2 x 8KB
    const int widx0 = (t >> 5) * 64 + (t & 31);        // this thread's w0 slot
    const int widx1 = widx0 + 32;

    // A-frags + x2 for the wave's two 32-row x-tiles.
    s16x8 af[2];
    float x2j[2];
    #pragma unroll
    for (int j = 0; j < 2; ++j) {
        const int xi = xbase + j * 32 + m32;
        const float c0 = xp[xi * 3], c1 = xp[xi * 3 + 1], c2 = xp[xi * 3 + 2];
        x2j[j] = c0 * c0 + c1 * c1 + c2 * c2;
        const unsigned int xh0 = bft(c0), xh1 = bft(c1), xh2 = bft(c2);
        const unsigned int xl0 = bft(c0 - bfv(xh0));
        const unsigned int xl1 = bft(c1 - bfv(xh1));
        const unsigned int xl2 = bft(c2 - bfv(xh2));
        s16x8 a;                                       // k = hh*8 + e
        a[0] = (short)(hh ? xl2 : xh0);
        a[1] = (short)(hh ? 0x3F80u : xh1);            // 1.0 bf16 (y2h)
        a[2] = (short)(hh ? 0x3F80u : xh2);            // 1.0 bf16 (y2l)
        a[3] = (short)(hh ? 0u : xh0);
        a[4] = (short)(hh ? 0u : xh1);
        a[5] = (short)(hh ? 0u : xh2);
        a[6] = (short)(hh ? 0u : xl0);
        a[7] = (short)(hh ? 0u : xl1);
        af[j] = a;
    }

    f32x16 zero, mn0, mn1;
    #pragma unroll
    for (int r = 0; r < 16; ++r) { zero[r] = 0.f; mn0[r] = 3.4e38f; mn1[r] = 3.4e38f; }

    // Prologue: prep phase 0 into buf0; load raw y for phase 1.
    const int pt0 = sl * YPS + t;                      // this thread's point, phase 0
    {
        const float a0 = yp[pt0 * 3], a1 = yp[pt0 * 3 + 1], a2 = yp[pt0 * 3 + 2];
        uint4 q0, q1;
        yfrag(a0, a1, a2, q0, q1);
        ldsb[0][widx0] = q0;
        ldsb[0][widx1] = q1;
    }
    float ry0 = yp[(pt0 + 256) * 3];
    float ry1 = yp[(pt0 + 256) * 3 + 1];
    float ry2 = yp[(pt0 + 256) * 3 + 2];
    __syncthreads();

    // 8 phases, double-buffered: compute phase c from buf[c&1] while writing
    // phase c+1 frags into buf[(c+1)&1] and issuing raw loads for phase c+2.
#define PAIR_COMPUTE(B0, B1)                                                          \
    do {                                                                              \
        const s16x8 bf0 = __builtin_bit_cast(s16x8, (B0));                            \
        const s16x8 bf1 = __builtin_bit_cast(s16x8, (B1));                            \
        const f32x16 e00 = __builtin_amdgcn_mfma_f32_32x32x16_bf16(af[0], bf0, zero, 0, 0, 0); \
        const f32x16 e01 = __builtin_amdgcn_mfma_f32_32x32x16_bf16(af[0], bf1, zero, 0, 0, 0); \
        mn0 = __builtin_elementwise_min(mn0, __builtin_elementwise_min(e00, e01));    \
        const f32x16 e10 = __builtin_amdgcn_mfma_f32_32x32x16_bf16(af[1], bf0, zero, 0, 0, 0); \
        const f32x16 e11 = __builtin_amdgcn_mfma_f32_32x32x16_bf16(af[1], bf1, zero, 0, 0, 0); \
        mn1 = __builtin_elementwise_min(mn1, __builtin_elementwise_min(e10, e11));    \
    } while (0)

    for (int c = 0; c < NPH - 1; ++c) {
        // frag math for phase c+1 (consumes ry), then free ry for c+2 loads
        uint4 q0, q1;
        yfrag(ry0, ry1, ry2, q0, q1);
        if (c < NPH - 2) {
            const int p = pt0 + (c + 2) * 256;
            ry0 = yp[p * 3]; ry1 = yp[p * 3 + 1]; ry2 = yp[p * 3 + 2];
        }
        uint4* wbuf = ldsb[(c + 1) & 1];
        wbuf[widx0] = q0;
        wbuf[widx1] = q1;
        // compute phase c (8 tiles = 4 pairs)
        const uint4* buf = ldsb[c & 1];
        #pragma unroll
        for (int p = 0; p < CTILES / 2; ++p)
            PAIR_COMPUTE(buf[(2 * p) * 64 + l], buf[(2 * p + 1) * 64 + l]);
        __syncthreads();
    }
    {   // tail phase
        const uint4* buf = ldsb[(NPH - 1) & 1];
        #pragma unroll
        for (int p = 0; p < CTILES / 2; ++p)
            PAIR_COMPUTE(buf[(2 * p) * 64 + l], buf[(2 * p + 1) * 64 + l]);
    }
#undef PAIR_COMPUTE

    // Butterfly min across the 32 cols (stays within each 32-lane half).
    #pragma unroll
    for (int off = 16; off; off >>= 1) {
        #pragma unroll
        for (int r = 0; r < 16; ++r) {
            mn0[r] = fminf(mn0[r], __shfl_xor(mn0[r], off, 64));
            mn1[r] = fminf(mn1[r], __shfl_xor(mn1[r], off, 64));
        }
    }

    // Lane l: r = l&15; lanes (l&31)<16 -> tile0, else tile1. One atomic/lane.
    const int r = l & 15;
    const int row = (r & 3) + 8 * (r >> 2) + 4 * hh;   // C/D row map (m74/m101)
    float v0 = mn0[0], v1 = mn1[0];
    #pragma unroll
    for (int rr = 1; rr < 16; ++rr) {
        v0 = (r == rr) ? mn0[rr] : v0;
        v1 = (r == rr) ? mn1[rr] : v1;
    }
    const float x20 = __shfl(x2j[0], row, 64);
    const float x21 = __shfl(x2j[1], row, 64);
    const bool g1 = (l & 31) >= 16;
    const float d = fmaxf((g1 ? v1 : v0) + (g1 ? x21 : x20), 0.f);
    const int xpt = xbase + (g1 ? 32 : 0) + row;
    atomicMin(&pmin[(size_t)bd * NPTS + xpt], __float_as_uint(d));
}

// One 1024-thread block: 128 threads per bd; sum + max per bd; write out[0].
__global__ __launch_bounds__(1024)
void reduce_all(const unsigned int* __restrict__ pmin, float* __restrict__ out) {
    const int t  = threadIdx.x;
    const int bd = t >> 7;
    const int l  = t & 127;
    const uint4* base = (const uint4*)(pmin + (size_t)bd * NPTS);  // 2048 uint4/bd
    float sum = 0.f, mx = -1.f;
    #pragma unroll
    for (int i = 0; i < NPTS / 128 / 4; ++i) {         // 16 x 2KB coalesced
        const uint4 q = base[i * 128 + l];
        const float f0 = __uint_as_float(q.x), f1 = __uint_as_float(q.y);
        const float f2 = __uint_as_float(q.z), f3 = __uint_as_float(q.w);
        sum += (f0 + f1) + (f2 + f3);
        mx = fmaxf(mx, fmaxf(fmaxf(f0, f1), fmaxf(f2, f3)));
    }
    #pragma unroll
    for (int off = 32; off; off >>= 1) {
        sum += __shfl_down(sum, off, 64);
        mx = fmaxf(mx, __shfl_down(mx, off, 64));
    }
    __shared__ float ss[16], sm[16];
    if ((t & 63) == 0) { ss[t >> 6] = sum; sm[t >> 6] = mx; }
    __syncthreads();
    if (t == 0) {
        float acc = 0.f;
        #pragma unroll
        for (int d = 0; d < 8; ++d) {
            const float S = ss[2 * d] + ss[2 * d + 1];
            const float M = fmaxf(sm[2 * d], sm[2 * d + 1]);
            acc += S * (1.f / NPTS) + ((d & 1) ? 0.f : M);   // max only for pred2gt
        }
        out[0] = acc * (1.f / BATCH);
    }
}

extern "C" void kernel_launch(void* const* d_in, const int* in_sizes, int n_in,
                              void* d_out, int out_size, void* d_ws, size_t ws_size,
                              hipStream_t stream) {
    const float* pred = (const float*)d_in[0];
    const float* gt   = (const float*)d_in[1];

    unsigned int* pmin = (unsigned int*)d_ws;                       // 256 KB

    hipMemsetAsync(pmin, 0xFF, (size_t)2 * BATCH * NPTS * 4, stream);
    dim3 g1(NXC, YS, 2 * BATCH);   // 32 x 4 x 8 = 1024 blocks (4/CU)
    nn_fused<<<g1, TPB, 0, stream>>>(pred, gt, pmin);
    reduce_all<<<dim3(1), 1024, 0, stream>>>(pmin, (float*)d_out);
}

// Round 4
// 85.200 us; speedup vs baseline: 1.1654x; 1.1654x over previous
//
#include <hip/hip_runtime.h>

// ChamferLoss: B=4, N=M=8192, D=3, fp32.
// loss = mean_b[ mean(pred2gt) + mean(gt2pred) + max(pred2gt) ]
// R12: barrier-free hot loop. R11 counters (nn 47.5us, VALUBusy 58%, Mfma 13%,
//  occ 25%, conflicts 0, hbm ~0) => stall-bound, not pipe-bound. Fixes:
//  - one-shot 32KB LDS staging per 1024-pt stage, 2 stages, 3 barriers total
//    (was 8 barrier-locksteps with yfrag+ds_write on the critical path);
//  - hot loop = pure ds_read_b128 stream, fully unrolled static offsets;
//  - sequential mins mn=min(mn,e) (one MFMA-result operand per v_min; the
//    min(e00,e01) tree forced 2 acc-operands -> moves);
//  - plain stores to pmin[bd][sl][xpt] (unique writer) -> no atomics, no
//    memset dispatch; reduce_all min-combines 4 slices. 2 dispatches total.
//   A row m (K=16): [xh0..2, xh0..2, xl0..2, 1, 1, 0...]
//   B col n (K=16): [-2yh0..2, -2yl0..2, -2yh0..2, y2h, y2l, 0]
//   D = y2 - 2(xh.yh + xh.yl + xl.yh); d2 = x2 + min_y D  (xl.yl ~2^-18 dropped)

typedef short  s16x8  __attribute__((ext_vector_type(8)));
typedef float  f32x16 __attribute__((ext_vector_type(16)));

#define BATCH 4
#define NPTS  8192
#define TPB   256
#define YS    4                    // y slices per (b,dir)
#define YPS   (NPTS / YS)          // 2048 y-points per slice
#define STPTS 1024                 // y-points staged per stage (32 KB LDS)
#define STTILES (STPTS / 32)       // 32 y-tiles per stage
#define XPB   256                  // x per block: 4 waves x 2 tiles x 32
#define NXC   (NPTS / XPB)         // 32

__device__ __forceinline__ unsigned int bft(float f) { return __float_as_uint(f) >> 16; }
__device__ __forceinline__ float bfv(unsigned int s) { return __uint_as_float(s << 16); }

// Build the two packed B-frag words for one y point (math verified absmax 0).
__device__ __forceinline__ void yfrag(float a0, float a1, float a2,
                                      uint4& w0, uint4& w1) {
    const unsigned int yh0 = bft(a0), yh1 = bft(a1), yh2 = bft(a2);
    const float l0 = a0 - bfv(yh0), l1 = a1 - bfv(yh1), l2 = a2 - bfv(yh2);
    const unsigned int nh0 = bft(-2.f * bfv(yh0));     // exact in bf16
    const unsigned int nh1 = bft(-2.f * bfv(yh1));
    const unsigned int nh2 = bft(-2.f * bfv(yh2));
    const unsigned int nl0 = bft(-2.f * l0), nl1 = bft(-2.f * l1), nl2 = bft(-2.f * l2);
    const float y2 = a0 * a0 + a1 * a1 + a2 * a2;
    const unsigned int q2h = bft(y2);
    const unsigned int q2l = bft(y2 - bfv(q2h));
    w0.x = nh0 | (nh1 << 16);
    w0.y = nh2 | (nl0 << 16);
    w0.z = nl1 | (nl2 << 16);
    w0.w = nh0 | (nh1 << 16);
    w1.x = nh2 | (q2h << 16);
    w1.y = q2l;
    w1.z = 0u; w1.w = 0u;
}

__global__ __launch_bounds__(TPB, 4)
void nn_fused(const float* __restrict__ pred, const float* __restrict__ gt,
              float* __restrict__ pmin) {
    const int xc = blockIdx.x, sl = blockIdx.y, bd = blockIdx.z;
    const int b = bd >> 1, dir = bd & 1;
    const float* xp = (dir ? gt : pred) + (size_t)b * NPTS * 3;
    const float* yp = (dir ? pred : gt) + (size_t)b * NPTS * 3;

    const int t = threadIdx.x;
    const int w = t >> 6, l = t & 63;
    const int m32 = l & 31, hh = l >> 5;
    const int xbase = xc * XPB + w * 64;

    // One-shot staging buffer: [tile(32)][{0..31: w0(k0-7), 32..63: w1(k8-15)}]
    __shared__ uint4 ldsb[STTILES * 64];               // 32 KB

    // A-frags + x2 for the wave's two 32-row x-tiles.
    s16x8 af[2];
    float x2j[2];
    #pragma unroll
    for (int j = 0; j < 2; ++j) {
        const int xi = xbase + j * 32 + m32;
        const float c0 = xp[xi * 3], c1 = xp[xi * 3 + 1], c2 = xp[xi * 3 + 2];
        x2j[j] = c0 * c0 + c1 * c1 + c2 * c2;
        const unsigned int xh0 = bft(c0), xh1 = bft(c1), xh2 = bft(c2);
        const unsigned int xl0 = bft(c0 - bfv(xh0));
        const unsigned int xl1 = bft(c1 - bfv(xh1));
        const unsigned int xl2 = bft(c2 - bfv(xh2));
        s16x8 a;                                       // k = hh*8 + e
        a[0] = (short)(hh ? xl2 : xh0);
        a[1] = (short)(hh ? 0x3F80u : xh1);            // 1.0 bf16 (y2h)
        a[2] = (short)(hh ? 0x3F80u : xh2);            // 1.0 bf16 (y2l)
        a[3] = (short)(hh ? 0u : xh0);
        a[4] = (short)(hh ? 0u : xh1);
        a[5] = (short)(hh ? 0u : xh2);
        a[6] = (short)(hh ? 0u : xl0);
        a[7] = (short)(hh ? 0u : xl1);
        af[j] = a;
    }

    f32x16 zero, mn0, mn1;
    #pragma unroll
    for (int r = 0; r < 16; ++r) { zero[r] = 0.f; mn0[r] = 3.4e38f; mn1[r] = 3.4e38f; }

    const uint4* bp = ldsb + l;                        // lane's fixed k-half slot

    for (int s = 0; s < 2; ++s) {
        if (s) __syncthreads();                        // stage-0 reads all done
        // Stage: 4 points/thread -> frags into LDS.
        #pragma unroll
        for (int i = 0; i < 4; ++i) {
            const int p = i * 256 + t;                 // 0..1023 within stage
            const int pt = sl * YPS + s * STPTS + p;
            const float a0 = yp[pt * 3], a1 = yp[pt * 3 + 1], a2 = yp[pt * 3 + 2];
            uint4 q0, q1;
            yfrag(a0, a1, a2, q0, q1);
            ldsb[(p >> 5) * 64 + (p & 31)]      = q0;
            ldsb[(p >> 5) * 64 + 32 + (p & 31)] = q1;
        }
        __syncthreads();
        // Barrier-free compute: 32 tiles, 2/step, 4 MFMAs in flight,
        // sequential mins (one MFMA-result operand per v_min).
        #pragma unroll
        for (int tp = 0; tp < STTILES; tp += 2) {
            const s16x8 bfa = __builtin_bit_cast(s16x8, bp[tp * 64]);
            const s16x8 bfb = __builtin_bit_cast(s16x8, bp[(tp + 1) * 64]);
            const f32x16 e0a = __builtin_amdgcn_mfma_f32_32x32x16_bf16(af[0], bfa, zero, 0, 0, 0);
            const f32x16 e1a = __builtin_amdgcn_mfma_f32_32x32x16_bf16(af[1], bfa, zero, 0, 0, 0);
            const f32x16 e0b = __builtin_amdgcn_mfma_f32_32x32x16_bf16(af[0], bfb, zero, 0, 0, 0);
            const f32x16 e1b = __builtin_amdgcn_mfma_f32_32x32x16_bf16(af[1], bfb, zero, 0, 0, 0);
            mn0 = __builtin_elementwise_min(mn0, e0a);
            mn1 = __builtin_elementwise_min(mn1, e1a);
            mn0 = __builtin_elementwise_min(mn0, e0b);
            mn1 = __builtin_elementwise_min(mn1, e1b);
        }
    }

    // Butterfly min across the 32 cols (stays within each 32-lane half).
    #pragma unroll
    for (int off = 16; off; off >>= 1) {
        #pragma unroll
        for (int r = 0; r < 16; ++r) {
            mn0[r] = fminf(mn0[r], __shfl_xor(mn0[r], off, 64));
            mn1[r] = fminf(mn1[r], __shfl_xor(mn1[r], off, 64));
        }
    }

    // Lane l: r = l&15; lanes (l&31)<16 -> tile0, else tile1. Unique writer
    // per (bd,sl,xpt) -> plain store, no atomic, no init.
    const int r = l & 15;
    const int row = (r & 3) + 8 * (r >> 2) + 4 * hh;   // C/D row map (m74/m101)
    float v0 = mn0[0], v1 = mn1[0];
    #pragma unroll
    for (int rr = 1; rr < 16; ++rr) {
        v0 = (r == rr) ? mn0[rr] : v0;
        v1 = (r == rr) ? mn1[rr] : v1;
    }
    const float x20 = __shfl(x2j[0], row, 64);
    const float x21 = __shfl(x2j[1], row, 64);
    const bool g1 = (l & 31) >= 16;
    const float d = fmaxf((g1 ? v1 : v0) + (g1 ? x21 : x20), 0.f);
    const int xpt = xbase + (g1 ? 32 : 0) + row;
    pmin[((size_t)bd * YS + sl) * NPTS + xpt] = d;
}

// One 1024-thread block: 128 threads per bd; min over 4 slices, sum + max.
__global__ __launch_bounds__(1024)
void reduce_all(const float* __restrict__ pmin, float* __restrict__ out) {
    const int t  = threadIdx.x;
    const int bd = t >> 7;
    const int l  = t & 127;
    const float4* base = (const float4*)(pmin + (size_t)bd * YS * NPTS);
    float sum = 0.f, mx = -1.f;
    #pragma unroll
    for (int i = 0; i < NPTS / 128 / 4; ++i) {         // 16 coalesced steps
        float4 q = base[i * 128 + l];
        #pragma unroll
        for (int s2 = 1; s2 < YS; ++s2) {
            const float4 rr = base[s2 * (NPTS / 4) + i * 128 + l];
            q.x = fminf(q.x, rr.x); q.y = fminf(q.y, rr.y);
            q.z = fminf(q.z, rr.z); q.w = fminf(q.w, rr.w);
        }
        sum += (q.x + q.y) + (q.z + q.w);
        mx = fmaxf(mx, fmaxf(fmaxf(q.x, q.y), fmaxf(q.z, q.w)));
    }
    #pragma unroll
    for (int off = 32; off; off >>= 1) {
        sum += __shfl_down(sum, off, 64);
        mx = fmaxf(mx, __shfl_down(mx, off, 64));
    }
    __shared__ float ss[16], sm[16];
    if ((t & 63) == 0) { ss[t >> 6] = sum; sm[t >> 6] = mx; }
    __syncthreads();
    if (t == 0) {
        float acc = 0.f;
        #pragma unroll
        for (int d = 0; d < 8; ++d) {
            const float S = ss[2 * d] + ss[2 * d + 1];
            const float M = fmaxf(sm[2 * d], sm[2 * d + 1]);
            acc += S * (1.f / NPTS) + ((d & 1) ? 0.f : M);   // max only for pred2gt
        }
        out[0] = acc * (1.f / BATCH);
    }
}

extern "C" void kernel_launch(void* const* d_in, const int* in_sizes, int n_in,
                              void* d_out, int out_size, void* d_ws, size_t ws_size,
                              hipStream_t stream) {
    const float* pred = (const float*)d_in[0];
    const float* gt   = (const float*)d_in[1];

    float* pmin = (float*)d_ws;                        // 8 * 4 * 8192 * 4B = 1 MB

    dim3 g1(NXC, YS, 2 * BATCH);   // 32 x 4 x 8 = 1024 blocks (4/CU)
    nn_fused<<<g1, TPB, 0, stream>>>(pred, gt, pmin);
    reduce_all<<<dim3(1), 1024, 0, stream>>>(pmin, (float*)d_out);
}

// Round 6
// 83.597 us; speedup vs baseline: 1.1877x; 1.0192x over previous
//
#include <hip/hip_runtime.h>

// ChamferLoss: B=4, N=M=8192, D=3, fp32.
// loss = mean_b[ mean(pred2gt) + mean(gt2pred) + max(pred2gt) ]
// R14: R12 structure (YS=4, launch_bounds(256,4), measured VGPR=64, conflicts
//  0, nn ~29-30us) + two safe levers:
//  - hot-loop mins as fminf(fminf(mn,ea),eb) elementwise -> v_min3_f32 fusion
//    halves the dominant VALU stream (64->32 ops/step); identical count if
//    unfused (no downside);
//  - parallel reduce: 64 blocks, per-bd atomicAdd/atomicMax + counter-gated
//    finalize (accum zeroed by nn block 0; same-stream ordering makes it safe).
//  NOT done: launch_bounds(256,8) (forces spill of 128 unified regs), raw-y
//  prefetch (12 live VGPRs across stage-0 compute risks 4->3 waves/SIMD).
//  Fixed overhead context: harness ws-poison fill ~40.6us/iter is in dur_us.
//   A row m (K=16): [xh0..2, xh0..2, xl0..2, 1, 1, 0...]
//   B col n (K=16): [-2yh0..2, -2yl0..2, -2yh0..2, y2h, y2l, 0]
//   D = y2 - 2(xh.yh + xh.yl + xl.yh); d2 = x2 + min_y D  (xl.yl ~2^-18 dropped)

typedef short  s16x8  __attribute__((ext_vector_type(8)));
typedef float  f32x16 __attribute__((ext_vector_type(16)));

#define BATCH 4
#define NPTS  8192
#define TPB   256
#define YS    4                    // y slices per (b,dir)
#define YPS   (NPTS / YS)          // 2048 y-points per slice
#define STPTS 1024                 // y-points staged per stage (32 KB LDS)
#define STTILES (STPTS / 32)       // 32 y-tiles per stage
#define XPB   256                  // x per block: 4 waves x 2 tiles x 32
#define NXC   (NPTS / XPB)         // 32
#define RBLK  64                   // reduce blocks

__device__ __forceinline__ unsigned int bft(float f) { return __float_as_uint(f) >> 16; }
__device__ __forceinline__ float bfv(unsigned int s) { return __uint_as_float(s << 16); }

// Build the two packed B-frag words for one y point (math verified absmax 0).
__device__ __forceinline__ void yfrag(float a0, float a1, float a2,
                                      uint4& w0, uint4& w1) {
    const unsigned int yh0 = bft(a0), yh1 = bft(a1), yh2 = bft(a2);
    const float l0 = a0 - bfv(yh0), l1 = a1 - bfv(yh1), l2 = a2 - bfv(yh2);
    const unsigned int nh0 = bft(-2.f * bfv(yh0));     // exact in bf16
    const unsigned int nh1 = bft(-2.f * bfv(yh1));
    const unsigned int nh2 = bft(-2.f * bfv(yh2));
    const unsigned int nl0 = bft(-2.f * l0), nl1 = bft(-2.f * l1), nl2 = bft(-2.f * l2);
    const float y2 = a0 * a0 + a1 * a1 + a2 * a2;
    const unsigned int q2h = bft(y2);
    const unsigned int q2l = bft(y2 - bfv(q2h));
    w0.x = nh0 | (nh1 << 16);
    w0.y = nh2 | (nl0 << 16);
    w0.z = nl1 | (nl2 << 16);
    w0.w = nh0 | (nh1 << 16);
    w1.x = nh2 | (q2h << 16);
    w1.y = q2l;
    w1.z = 0u; w1.w = 0u;
}

__global__ __launch_bounds__(TPB, 4)
void nn_fused(const float* __restrict__ pred, const float* __restrict__ gt,
              float* __restrict__ pmin, unsigned int* __restrict__ accum) {
    const int xc = blockIdx.x, sl = blockIdx.y, bd = blockIdx.z;
    const int t = threadIdx.x;
    // Zero the reduce accumulators (8 sums + 8 maxbits + counter). Safe:
    // reduce_all is a later dispatch on the same stream.
    if (xc == 0 && sl == 0 && bd == 0 && t < 17) accum[t] = 0u;

    const int b = bd >> 1, dir = bd & 1;
    const float* xp = (dir ? gt : pred) + (size_t)b * NPTS * 3;
    const float* yp = (dir ? pred : gt) + (size_t)b * NPTS * 3;

    const int w = t >> 6, l = t & 63;
    const int m32 = l & 31, hh = l >> 5;
    const int xbase = xc * XPB + w * 64;

    // One-shot staging buffer: [tile(32)][{0..31: w0(k0-7), 32..63: w1(k8-15)}]
    __shared__ uint4 ldsb[STTILES * 64];               // 32 KB

    // A-frags + x2 for the wave's two 32-row x-tiles.
    s16x8 af[2];
    float x2j[2];
    #pragma unroll
    for (int j = 0; j < 2; ++j) {
        const int xi = xbase + j * 32 + m32;
        const float c0 = xp[xi * 3], c1 = xp[xi * 3 + 1], c2 = xp[xi * 3 + 2];
        x2j[j] = c0 * c0 + c1 * c1 + c2 * c2;
        const unsigned int xh0 = bft(c0), xh1 = bft(c1), xh2 = bft(c2);
        const unsigned int xl0 = bft(c0 - bfv(xh0));
        const unsigned int xl1 = bft(c1 - bfv(xh1));
        const unsigned int xl2 = bft(c2 - bfv(xh2));
        s16x8 a;                                       // k = hh*8 + e
        a[0] = (short)(hh ? xl2 : xh0);
        a[1] = (short)(hh ? 0x3F80u : xh1);            // 1.0 bf16 (y2h)
        a[2] = (short)(hh ? 0x3F80u : xh2);            // 1.0 bf16 (y2l)
        a[3] = (short)(hh ? 0u : xh0);
        a[4] = (short)(hh ? 0u : xh1);
        a[5] = (short)(hh ? 0u : xh2);
        a[6] = (short)(hh ? 0u : xl0);
        a[7] = (short)(hh ? 0u : xl1);
        af[j] = a;
    }

    f32x16 zero, mn0, mn1;
    #pragma unroll
    for (int r = 0; r < 16; ++r) { zero[r] = 0.f; mn0[r] = 3.4e38f; mn1[r] = 3.4e38f; }

    const uint4* bp = ldsb + l;                        // lane's fixed k-half slot

    for (int s = 0; s < 2; ++s) {
        if (s) __syncthreads();                        // stage-0 reads all done
        // Stage: 4 points/thread -> frags into LDS.
        #pragma unroll
        for (int i = 0; i < 4; ++i) {
            const int p = i * 256 + t;                 // 0..1023 within stage
            const int pt = sl * YPS + s * STPTS + p;
            const float a0 = yp[pt * 3], a1 = yp[pt * 3 + 1], a2 = yp[pt * 3 + 2];
            uint4 q0, q1;
            yfrag(a0, a1, a2, q0, q1);
            ldsb[(p >> 5) * 64 + (p & 31)]      = q0;
            ldsb[(p >> 5) * 64 + 32 + (p & 31)] = q1;
        }
        __syncthreads();
        // Barrier-free compute: 32 tiles, 2/step, 4 MFMAs in flight.
        // Elementwise fminf chains -> v_min3_f32 fusion (halves VALU if fused,
        // identical instruction count if not).
        #pragma unroll
        for (int tp = 0; tp < STTILES; tp += 2) {
            const s16x8 bfa = __builtin_bit_cast(s16x8, bp[tp * 64]);
            const s16x8 bfb = __builtin_bit_cast(s16x8, bp[(tp + 1) * 64]);
            const f32x16 e0a = __builtin_amdgcn_mfma_f32_32x32x16_bf16(af[0], bfa, zero, 0, 0, 0);
            const f32x16 e1a = __builtin_amdgcn_mfma_f32_32x32x16_bf16(af[1], bfa, zero, 0, 0, 0);
            const f32x16 e0b = __builtin_amdgcn_mfma_f32_32x32x16_bf16(af[0], bfb, zero, 0, 0, 0);
            const f32x16 e1b = __builtin_amdgcn_mfma_f32_32x32x16_bf16(af[1], bfb, zero, 0, 0, 0);
            #pragma unroll
            for (int r = 0; r < 16; ++r) {
                mn0[r] = fminf(fminf(mn0[r], e0a[r]), e0b[r]);
                mn1[r] = fminf(fminf(mn1[r], e1a[r]), e1b[r]);
            }
        }
    }

    // Butterfly min across the 32 cols (stays within each 32-lane half).
    #pragma unroll
    for (int off = 16; off; off >>= 1) {
        #pragma unroll
        for (int r = 0; r < 16; ++r) {
            mn0[r] = fminf(mn0[r], __shfl_xor(mn0[r], off, 64));
            mn1[r] = fminf(mn1[r], __shfl_xor(mn1[r], off, 64));
        }
    }

    // Lane l: r = l&15; lanes (l&31)<16 -> tile0, else tile1. Unique writer
    // per (bd,sl,xpt) -> plain store, no atomic, no init.
    const int r = l & 15;
    const int row = (r & 3) + 8 * (r >> 2) + 4 * hh;   // C/D row map (m74/m101)
    float v0 = mn0[0], v1 = mn1[0];
    #pragma unroll
    for (int rr = 1; rr < 16; ++rr) {
        v0 = (r == rr) ? mn0[rr] : v0;
        v1 = (r == rr) ? mn1[rr] : v1;
    }
    const float x20 = __shfl(x2j[0], row, 64);
    const float x21 = __shfl(x2j[1], row, 64);
    const bool g1 = (l & 31) >= 16;
    const float d = fmaxf((g1 ? v1 : v0) + (g1 ? x21 : x20), 0.f);
    const int xpt = xbase + (g1 ? 32 : 0) + row;
    pmin[((size_t)bd * YS + sl) * NPTS + xpt] = d;
}

// 64 blocks x 256 threads. Block g: bd = g>>3, x-segment = g&7 (1024 pts).
// Min over YS slices, partial sum+max per block -> device atomics; last
// block finalizes out[0]. accum: [0..7] f32 sums, [8..15] u32 maxbits, [16] ctr.
__global__ __launch_bounds__(TPB)
void reduce_all(const float* __restrict__ pmin, float* __restrict__ accum,
                float* __restrict__ out) {
    const int g = blockIdx.x, bd = g >> 3, seg = g & 7;
    const int t = threadIdx.x;
    const float4* base = (const float4*)(pmin + (size_t)bd * YS * NPTS);
    const int f4 = seg * 256 + t;                      // float4 idx within slice
    float4 q = base[f4];
    #pragma unroll
    for (int sl = 1; sl < YS; ++sl) {
        const float4 rr = base[sl * (NPTS / 4) + f4];
        q.x = fminf(q.x, rr.x); q.y = fminf(q.y, rr.y);
        q.z = fminf(q.z, rr.z); q.w = fminf(q.w, rr.w);
    }
    float s = (q.x + q.y) + (q.z + q.w);
    float m = fmaxf(fmaxf(q.x, q.y), fmaxf(q.z, q.w));
    #pragma unroll
    for (int off = 32; off; off >>= 1) {
        s += __shfl_down(s, off, 64);
        m = fmaxf(m, __shfl_down(m, off, 64));
    }
    __shared__ float ws_[4], wm_[4];
    if ((t & 63) == 0) { ws_[t >> 6] = s; wm_[t >> 6] = m; }
    __syncthreads();
    if (t == 0) {
        s = (ws_[0] + ws_[1]) + (ws_[2] + ws_[3]);
        m = fmaxf(fmaxf(wm_[0], wm_[1]), fmaxf(wm_[2], wm_[3]));
        atomicAdd(&accum[bd], s);
        atomicMax((unsigned int*)accum + 8 + bd, __float_as_uint(m));  // d>=0
        __threadfence();
        const unsigned int done = atomicAdd((unsigned int*)accum + 16, 1u);
        if (done == RBLK - 1) {
            float acc = 0.f;
            #pragma unroll
            for (int b2 = 0; b2 < BATCH; ++b2) {
                const float s0 = atomicAdd(&accum[2 * b2], 0.f);      // coherent read
                const float s1 = atomicAdd(&accum[2 * b2 + 1], 0.f);
                const unsigned int mb =
                    atomicMax((unsigned int*)accum + 8 + 2 * b2, 0u); // pred2gt max
                acc += (s0 + s1) * (1.f / NPTS) + __uint_as_float(mb);
            }
            out[0] = acc * (1.f / BATCH);
        }
    }
}

extern "C" void kernel_launch(void* const* d_in, const int* in_sizes, int n_in,
                              void* d_out, int out_size, void* d_ws, size_t ws_size,
                              hipStream_t stream) {
    const float* pred = (const float*)d_in[0];
    const float* gt   = (const float*)d_in[1];

    float* pmin = (float*)d_ws;                        // 8 * 4 * 8192 * 4B = 1 MB
    float* accum = (float*)((char*)d_ws + (size_t)2 * BATCH * YS * NPTS * 4);

    dim3 g1(NXC, YS, 2 * BATCH);   // 32 x 4 x 8 = 1024 blocks (4/CU)
    nn_fused<<<g1, TPB, 0, stream>>>(pred, gt, pmin, (unsigned int*)accum);
    reduce_all<<<dim3(RBLK), TPB, 0, stream>>>(pmin, accum, (float*)d_out);
}

// Round 8
// 82.139 us; speedup vs baseline: 1.2088x; 1.0178x over previous
//
#include <hip/hip_runtime.h>

// ChamferLoss: B=4, N=M=8192, D=3, fp32.
// loss = mean_b[ mean(pred2gt) + mean(gt2pred) + max(pred2gt) ]
// R16 = R15 resubmitted (GPU acquisition timed out; experiment unmeasured).
// R15: register-pressure fix. R11/R12 counters: Occupancy ~25% = 2 waves/SIMD.
//  Unified-file accounting: mn(32)+4 e-bufs(64)+zero(16)+misc ~190 regs/wave
//  -> 2 waves/SIMD (m69 steps), latency-bound everywhere (why R14's min3 was
//  neutral). Fix: two SEQUENTIAL fold groups per step, only 2 e-buffers live
//  at once -> ~116 regs peak, launch_bounds cap 128 satisfiable, 4 waves/SIMD.
//  Keep min3 pairing (VALU floor 3.4us device-wide), 32KB one-shot staging,
//  parallel 64-block reduce. Fixed ~40us harness ws-poison fill is in dur_us.
//   A row m (K=16): [xh0..2, xh0..2, xl0..2, 1, 1, 0...]
//   B col n (K=16): [-2yh0..2, -2yl0..2, -2yh0..2, y2h, y2l, 0]
//   D = y2 - 2(xh.yh + xh.yl + xl.yh); d2 = x2 + min_y D  (xl.yl ~2^-18 dropped)

typedef short  s16x8  __attribute__((ext_vector_type(8)));
typedef float  f32x16 __attribute__((ext_vector_type(16)));

#define BATCH 4
#define NPTS  8192
#define TPB   256
#define YS    4                    // y slices per (b,dir)
#define YPS   (NPTS / YS)          // 2048 y-points per slice
#define STPTS 1024                 // y-points staged per stage (32 KB LDS)
#define STTILES (STPTS / 32)       // 32 y-tiles per stage
#define XPB   256                  // x per block: 4 waves x 2 tiles x 32
#define NXC   (NPTS / XPB)         // 32
#define RBLK  64                   // reduce blocks

__device__ __forceinline__ unsigned int bft(float f) { return __float_as_uint(f) >> 16; }
__device__ __forceinline__ float bfv(unsigned int s) { return __uint_as_float(s << 16); }

// Build the two packed B-frag words for one y point (math verified absmax 0).
__device__ __forceinline__ void yfrag(float a0, float a1, float a2,
                                      uint4& w0, uint4& w1) {
    const unsigned int yh0 = bft(a0), yh1 = bft(a1), yh2 = bft(a2);
    const float l0 = a0 - bfv(yh0), l1 = a1 - bfv(yh1), l2 = a2 - bfv(yh2);
    const unsigned int nh0 = bft(-2.f * bfv(yh0));     // exact in bf16
    const unsigned int nh1 = bft(-2.f * bfv(yh1));
    const unsigned int nh2 = bft(-2.f * bfv(yh2));
    const unsigned int nl0 = bft(-2.f * l0), nl1 = bft(-2.f * l1), nl2 = bft(-2.f * l2);
    const float y2 = a0 * a0 + a1 * a1 + a2 * a2;
    const unsigned int q2h = bft(y2);
    const unsigned int q2l = bft(y2 - bfv(q2h));
    w0.x = nh0 | (nh1 << 16);
    w0.y = nh2 | (nl0 << 16);
    w0.z = nl1 | (nl2 << 16);
    w0.w = nh0 | (nh1 << 16);
    w1.x = nh2 | (q2h << 16);
    w1.y = q2l;
    w1.z = 0u; w1.w = 0u;
}

__global__ __launch_bounds__(TPB, 4)
void nn_fused(const float* __restrict__ pred, const float* __restrict__ gt,
              float* __restrict__ pmin, unsigned int* __restrict__ accum) {
    const int xc = blockIdx.x, sl = blockIdx.y, bd = blockIdx.z;
    const int t = threadIdx.x;
    // Zero the reduce accumulators (8 sums + 8 maxbits + counter). Safe:
    // reduce_all is a later dispatch on the same stream.
    if (xc == 0 && sl == 0 && bd == 0 && t < 17) accum[t] = 0u;

    const int b = bd >> 1, dir = bd & 1;
    const float* xp = (dir ? gt : pred) + (size_t)b * NPTS * 3;
    const float* yp = (dir ? pred : gt) + (size_t)b * NPTS * 3;

    const int w = t >> 6, l = t & 63;
    const int m32 = l & 31, hh = l >> 5;
    const int xbase = xc * XPB + w * 64;

    // One-shot staging buffer: [tile(32)][{0..31: w0(k0-7), 32..63: w1(k8-15)}]
    __shared__ uint4 ldsb[STTILES * 64];               // 32 KB

    // A-frags + x2 for the wave's two 32-row x-tiles.
    s16x8 af[2];
    float x2j[2];
    #pragma unroll
    for (int j = 0; j < 2; ++j) {
        const int xi = xbase + j * 32 + m32;
        const float c0 = xp[xi * 3], c1 = xp[xi * 3 + 1], c2 = xp[xi * 3 + 2];
        x2j[j] = c0 * c0 + c1 * c1 + c2 * c2;
        const unsigned int xh0 = bft(c0), xh1 = bft(c1), xh2 = bft(c2);
        const unsigned int xl0 = bft(c0 - bfv(xh0));
        const unsigned int xl1 = bft(c1 - bfv(xh1));
        const unsigned int xl2 = bft(c2 - bfv(xh2));
        s16x8 a;                                       // k = hh*8 + e
        a[0] = (short)(hh ? xl2 : xh0);
        a[1] = (short)(hh ? 0x3F80u : xh1);            // 1.0 bf16 (y2h)
        a[2] = (short)(hh ? 0x3F80u : xh2);            // 1.0 bf16 (y2l)
        a[3] = (short)(hh ? 0u : xh0);
        a[4] = (short)(hh ? 0u : xh1);
        a[5] = (short)(hh ? 0u : xh2);
        a[6] = (short)(hh ? 0u : xl0);
        a[7] = (short)(hh ? 0u : xl1);
        af[j] = a;
    }

    f32x16 zero, mn0, mn1;
    #pragma unroll
    for (int r = 0; r < 16; ++r) { zero[r] = 0.f; mn0[r] = 3.4e38f; mn1[r] = 3.4e38f; }

    const uint4* bp = ldsb + l;                        // lane's fixed k-half slot

    for (int s = 0; s < 2; ++s) {
        if (s) __syncthreads();                        // stage-0 reads all done
        // Stage: 4 points/thread -> frags into LDS.
        #pragma unroll
        for (int i = 0; i < 4; ++i) {
            const int p = i * 256 + t;                 // 0..1023 within stage
            const int pt = sl * YPS + s * STPTS + p;
            const float a0 = yp[pt * 3], a1 = yp[pt * 3 + 1], a2 = yp[pt * 3 + 2];
            uint4 q0, q1;
            yfrag(a0, a1, a2, q0, q1);
            ldsb[(p >> 5) * 64 + (p & 31)]      = q0;
            ldsb[(p >> 5) * 64 + 32 + (p & 31)] = q1;
        }
        __syncthreads();
        // Barrier-free compute: 32 tiles, 2/step. Two SEQUENTIAL fold groups:
        // only 2 e-buffers live at any point (register-pressure fix), min3
        // fusion folds 2 MFMA results per VALU op.
        #pragma unroll
        for (int tp = 0; tp < STTILES; tp += 2) {
            const s16x8 bfa = __builtin_bit_cast(s16x8, bp[tp * 64]);
            const s16x8 bfb = __builtin_bit_cast(s16x8, bp[(tp + 1) * 64]);
            {   // group 0: x-tile 0 vs y-tiles a,b
                const f32x16 e0a = __builtin_amdgcn_mfma_f32_32x32x16_bf16(af[0], bfa, zero, 0, 0, 0);
                const f32x16 e0b = __builtin_amdgcn_mfma_f32_32x32x16_bf16(af[0], bfb, zero, 0, 0, 0);
                #pragma unroll
                for (int r = 0; r < 16; ++r)
                    mn0[r] = fminf(fminf(mn0[r], e0a[r]), e0b[r]);
            }
            {   // group 1: x-tile 1 vs y-tiles a,b
                const f32x16 e1a = __builtin_amdgcn_mfma_f32_32x32x16_bf16(af[1], bfa, zero, 0, 0, 0);
                const f32x16 e1b = __builtin_amdgcn_mfma_f32_32x32x16_bf16(af[1], bfb, zero, 0, 0, 0);
                #pragma unroll
                for (int r = 0; r < 16; ++r)
                    mn1[r] = fminf(fminf(mn1[r], e1a[r]), e1b[r]);
            }
        }
    }

    // Butterfly min across the 32 cols (stays within each 32-lane half).
    #pragma unroll
    for (int off = 16; off; off >>= 1) {
        #pragma unroll
        for (int r = 0; r < 16; ++r) {
            mn0[r] = fminf(mn0[r], __shfl_xor(mn0[r], off, 64));
            mn1[r] = fminf(mn1[r], __shfl_xor(mn1[r], off, 64));
        }
    }

    // Lane l: r = l&15; lanes (l&31)<16 -> tile0, else tile1. Unique writer
    // per (bd,sl,xpt) -> plain store, no atomic, no init.
    const int r = l & 15;
    const int row = (r & 3) + 8 * (r >> 2) + 4 * hh;   // C/D row map (m74/m101)
    float v0 = mn0[0], v1 = mn1[0];
    #pragma unroll
    for (int rr = 1; rr < 16; ++rr) {
        v0 = (r == rr) ? mn0[rr] : v0;
        v1 = (r == rr) ? mn1[rr] : v1;
    }
    const float x20 = __shfl(x2j[0], row, 64);
    const float x21 = __shfl(x2j[1], row, 64);
    const bool g1 = (l & 31) >= 16;
    const float d = fmaxf((g1 ? v1 : v0) + (g1 ? x21 : x20), 0.f);
    const int xpt = xbase + (g1 ? 32 : 0) + row;
    pmin[((size_t)bd * YS + sl) * NPTS + xpt] = d;
}

// 64 blocks x 256 threads. Block g: bd = g>>3, x-segment = g&7 (1024 pts).
// Min over YS slices, partial sum+max per block -> device atomics; last
// block finalizes out[0]. accum: [0..7] f32 sums, [8..15] u32 maxbits, [16] ctr.
__global__ __launch_bounds__(TPB)
void reduce_all(const float* __restrict__ pmin, float* __restrict__ accum,
                float* __restrict__ out) {
    const int g = blockIdx.x, bd = g >> 3, seg = g & 7;
    const int t = threadIdx.x;
    const float4* base = (const float4*)(pmin + (size_t)bd * YS * NPTS);
    const int f4 = seg * 256 + t;                      // float4 idx within slice
    float4 q = base[f4];
    #pragma unroll
    for (int sl = 1; sl < YS; ++sl) {
        const float4 rr = base[sl * (NPTS / 4) + f4];
        q.x = fminf(q.x, rr.x); q.y = fminf(q.y, rr.y);
        q.z = fminf(q.z, rr.z); q.w = fminf(q.w, rr.w);
    }
    float s = (q.x + q.y) + (q.z + q.w);
    float m = fmaxf(fmaxf(q.x, q.y), fmaxf(q.z, q.w));
    #pragma unroll
    for (int off = 32; off; off >>= 1) {
        s += __shfl_down(s, off, 64);
        m = fmaxf(m, __shfl_down(m, off, 64));
    }
    __shared__ float ws_[4], wm_[4];
    if ((t & 63) == 0) { ws_[t >> 6] = s; wm_[t >> 6] = m; }
    __syncthreads();
    if (t == 0) {
        s = (ws_[0] + ws_[1]) + (ws_[2] + ws_[3]);
        m = fmaxf(fmaxf(wm_[0], wm_[1]), fmaxf(wm_[2], wm_[3]));
        atomicAdd(&accum[bd], s);
        atomicMax((unsigned int*)accum + 8 + bd, __float_as_uint(m));  // d>=0
        __threadfence();
        const unsigned int done = atomicAdd((unsigned int*)accum + 16, 1u);
        if (done == RBLK - 1) {
            float acc = 0.f;
            #pragma unroll
            for (int b2 = 0; b2 < BATCH; ++b2) {
                const float s0 = atomicAdd(&accum[2 * b2], 0.f);      // coherent read
                const float s1 = atomicAdd(&accum[2 * b2 + 1], 0.f);
                const unsigned int mb =
                    atomicMax((unsigned int*)accum + 8 + 2 * b2, 0u); // pred2gt max
                acc += (s0 + s1) * (1.f / NPTS) + __uint_as_float(mb);
            }
            out[0] = acc * (1.f / BATCH);
        }
    }
}

extern "C" void kernel_launch(void* const* d_in, const int* in_sizes, int n_in,
                              void* d_out, int out_size, void* d_ws, size_t ws_size,
                              hipStream_t stream) {
    const float* pred = (const float*)d_in[0];
    const float* gt   = (const float*)d_in[1];

    float* pmin = (float*)d_ws;                        // 8 * 4 * 8192 * 4B = 1 MB
    float* accum = (float*)((char*)d_ws + (size_t)2 * BATCH * YS * NPTS * 4);

    dim3 g1(NXC, YS, 2 * BATCH);   // 32 x 4 x 8 = 1024 blocks (4/CU)
    nn_fused<<<g1, TPB, 0, stream>>>(pred, gt, pmin, (unsigned int*)accum);
    reduce_all<<<dim3(RBLK), TPB, 0, stream>>>(pmin, accum, (float*)d_out);
}